// Round 6
// baseline (1714.581 us; speedup 1.0000x reference)
//
#include <hip/hip_runtime.h>
#include <hip/hip_bf16.h>
#include <stdint.h>

// Problem constants (fixed by the reference)
#define B_   4
#define H_   8
#define SQ_  2048
#define SK_  512
#define DM_  4096
#define DK_  512

typedef __bf16 bf16;
typedef __bf16 bf16x8 __attribute__((ext_vector_type(8)));
typedef float  fx4    __attribute__((ext_vector_type(4)));

// address-space-qualified pointer types for global_load_lds
typedef __attribute__((address_space(1))) void gv_t;   // global
typedef __attribute__((address_space(3))) void lv_t;   // LDS

// ---------------------------------------------------------------------------
// Dtype sniffer (unchanged). flag=1 -> external tensors are fp32.
__global__ void sniff_dtype(const uint32_t* __restrict__ q, int* __restrict__ flag)
{
    const int l = threadIdx.x;  // 64 lanes
    int cnt = 0;
    #pragma unroll
    for (int i = 0; i < 4; ++i) {
        const uint32_t u = q[l * 4 + i];
        const int e = (u >> 7) & 0xFF;
        cnt += (e >= 100 && e <= 135) ? 1 : 0;
    }
    #pragma unroll
    for (int s = 1; s < 64; s <<= 1) cnt += __shfl_xor(cnt, s);
    if (l == 0) *flag = (cnt < 150) ? 1 : 0;
}

// ---------------------------------------------------------------------------
// One-time dtype normalization: fp32 -> bf16 (or bf16 passthrough copy).
__global__ __launch_bounds__(256) void cvt_to_bf16(
    const void* __restrict__ in, bf16* __restrict__ out, const int* __restrict__ flagp)
{
    const size_t i = ((size_t)blockIdx.x * 256 + threadIdx.x) * 8;
    if (*flagp) {
        const float4* p = (const float4*)((const float*)in + i);
        const float4 u0 = p[0], u1 = p[1];
        bf16x8 v;
        v[0] = (bf16)u0.x; v[1] = (bf16)u0.y; v[2] = (bf16)u0.z; v[3] = (bf16)u0.w;
        v[4] = (bf16)u1.x; v[5] = (bf16)u1.y; v[6] = (bf16)u1.z; v[7] = (bf16)u1.w;
        *(bf16x8*)(out + i) = v;
    } else {
        *(bf16x8*)(out + i) = *(const bf16x8*)((const bf16*)in + i);
    }
}

// ---------------------------------------------------------------------------
// 128^2-tile GEMM (verified rounds 0-1). Kept for the three M=2048 projections.
__global__ __launch_bounds__(256, 3) void gemm_bt(
    const bf16* __restrict__ A, const bf16* __restrict__ Bt,
    void* __restrict__ Cv, const void* __restrict__ biasv,
    int K, int lda, int ldb, int ldc, float alpha,
    long long sAb, long long sAh, long long sBb, long long sBh,
    long long sCb, long long sCh,
    const int* __restrict__ flagp, int ebits)
{
    __shared__ bf16 sA[128 * 64];
    __shared__ bf16 sB[128 * 64];

    const int fl = ebits ? *flagp : 0;
    const bool bias32 = fl && (ebits & 1);
    const bool c32    = fl && (ebits & 2);

    const int z = blockIdx.z;
    const int bz = z >> 3, hz = z & 7;
    const bf16* Ab = A  + (size_t)bz * sAb + (size_t)hz * sAh;
    const bf16* Bb = Bt + (size_t)bz * sBb + (size_t)hz * sBh;
    const size_t offC = (size_t)bz * sCb + (size_t)hz * sCh;

    const int n0 = blockIdx.x * 128;
    const int m0 = blockIdx.y * 128;

    const int t = threadIdx.x;
    const int w = t >> 6, l = t & 63;
    const int lrow = l >> 3, lcol = l & 7;
    const int wm = (w >> 1) * 64, wn = (w & 1) * 64;
    const int ml = l & 15, quad = l >> 4;

    const bf16* pa[4];
    const bf16* pb[4];
    #pragma unroll
    for (int i = 0; i < 4; ++i) {
        const int c = w * 4 + i;
        const int r = c * 8 + lrow;
        const int jj = lcol ^ (r & 7);
        pa[i] = Ab + (size_t)(m0 + r) * lda + jj * 8;
        pb[i] = Bb + (size_t)(n0 + r) * ldb + jj * 8;
    }

    fx4 acc[4][4];
    const fx4 zero = {0.f, 0.f, 0.f, 0.f};
    #pragma unroll
    for (int i = 0; i < 4; ++i)
        #pragma unroll
        for (int j = 0; j < 4; ++j) acc[i][j] = zero;

    for (int kt = 0; kt < K; kt += 64) {
        #pragma unroll
        for (int i = 0; i < 4; ++i) {
            const int c = w * 4 + i;
            __builtin_amdgcn_global_load_lds((gv_t*)(pa[i] + kt), (lv_t*)(sA + c * 512), 16, 0, 0);
            __builtin_amdgcn_global_load_lds((gv_t*)(pb[i] + kt), (lv_t*)(sB + c * 512), 16, 0, 0);
        }
        __syncthreads();

        #pragma unroll
        for (int kk = 0; kk < 64; kk += 32) {
            bf16x8 af[4], bfr[4];
            const int jbase = (kk >> 3) + quad;
            #pragma unroll
            for (int mi = 0; mi < 4; ++mi) {
                const int r = wm + mi * 16 + ml;
                af[mi] = *(const bf16x8*)&sA[r * 64 + ((jbase ^ (r & 7)) << 3)];
            }
            #pragma unroll
            for (int ni = 0; ni < 4; ++ni) {
                const int r = wn + ni * 16 + ml;
                bfr[ni] = *(const bf16x8*)&sB[r * 64 + ((jbase ^ (r & 7)) << 3)];
            }
            #pragma unroll
            for (int mi = 0; mi < 4; ++mi)
                #pragma unroll
                for (int ni = 0; ni < 4; ++ni)
                    acc[mi][ni] = __builtin_amdgcn_mfma_f32_16x16x32_bf16(
                        af[mi], bfr[ni], acc[mi][ni], 0, 0, 0);
        }
        __syncthreads();
    }

    #pragma unroll
    for (int ni = 0; ni < 4; ++ni) {
        const int cg = n0 + wn + ni * 16 + ml;
        const float bv = biasv ? (bias32 ? ((const float*)biasv)[cg] : (float)((const bf16*)biasv)[cg]) : 0.f;
        #pragma unroll
        for (int mi = 0; mi < 4; ++mi) {
            const int rg = m0 + wm + mi * 16 + quad * 4;
            #pragma unroll
            for (int r = 0; r < 4; ++r) {
                const float val = acc[mi][ni][r] * alpha + bv;
                const size_t idx = offC + (size_t)(rg + r) * ldc + cg;
                if (c32) ((float*)Cv)[idx] = val;
                else     ((bf16*)Cv)[idx] = (bf16)val;
            }
        }
    }
}

// ---------------------------------------------------------------------------
// gemm_pipe (round 6): 256x128 tile, BK=32, 256 threads = 4 waves (2x1 grid of
// 128x64 per-wave tiles), double-buffered 48 KiB LDS -> **2 independent WGs
// per CU**. Round-5 post-mortem: with 1 WG/CU all 8 waves are barrier-locked
// into the same window, so LDS pipe (reads 2304 + DMA writes ~500 cyc/tile)
// and matrix pipe (2483) fully SERIALIZE (measured 6280 cyc/tile, 34%).
// Two unsynchronized WGs/CU restore the m114/m97 overlap mechanism: one WG's
// read window covers the other's MFMA window. Per-wave read ratio kept at
// 0.375 (12 ds_read_b128 per 32 MFMA, Gray order). Counted vmcnt (6 loads/
// tile, 2-tile lookahead, vmcnt(6)) + 2 raw barriers/tile, as verified in
// rounds 3-5.
// LDS row = 32 elems (64 B) = 4 x 16B slots. Swizzle: global col-group
// jj = (l&3) ^ ((r>>1)&3) stored at linear slot l&3; read slot
// quad ^ ((fr>>1)&3). Bank check: 16-lane fragment group spans
// (fr&1)*16 + slot*4 -> 8 distinct 4-bank groups x 2 lanes = 2-way (free).
#define ISSUE_TILE6(tt, bb)                                                         \
    do {                                                                            \
        bf16* bufA_ = sm + (bb) * 12288;                                            \
        bf16* bufB_ = bufA_ + 8192;                                                 \
        _Pragma("unroll")                                                           \
        for (int i_ = 0; i_ < 4; ++i_)                                              \
            __builtin_amdgcn_global_load_lds((gv_t*)(pa[i_] + (size_t)(tt) * 32),   \
                (lv_t*)(bufA_ + (w * 4 + i_) * 512), 16, 0, 0);                     \
        _Pragma("unroll")                                                           \
        for (int i_ = 0; i_ < 2; ++i_)                                              \
            __builtin_amdgcn_global_load_lds((gv_t*)(pb[i_] + (size_t)(tt) * 32),   \
                (lv_t*)(bufB_ + (w * 2 + i_) * 512), 16, 0, 0);                     \
    } while (0)

// fragment read: row fr, k-group = quad, slot = quad ^ ((fr>>1)&3)
#define LDS_FRAG32(dst, base, fr)                                                   \
    dst = *(const bf16x8*)&base[(fr) * 32 + (((quad ^ (((fr) >> 1) & 3))) << 3)]

__global__ __launch_bounds__(256, 2) void gemm_pipe(
    const bf16* __restrict__ A, const bf16* __restrict__ Bt,
    void* __restrict__ Cv, const void* __restrict__ biasv,
    int K, int lda, int ldb, int ldc, float alpha,
    long long sAb, long long sAh, long long sBb, long long sBh,
    long long sCb, long long sCh,
    const int* __restrict__ flagp, int ebits)
{
    __shared__ bf16 sm[2 * 12288];   // per buf: A 256x32 (8192) + B 128x32 (4096) = 48 KiB

    const int fl = ebits ? *flagp : 0;
    const bool bias32 = fl && (ebits & 1);
    const bool c32    = fl && (ebits & 2);

    // ---- XCD-bijective block swizzle (all grids here are %8==0) ----
    const int gX = gridDim.x, gY = gridDim.y;
    int idx = (blockIdx.z * gY + blockIdx.y) * gX + blockIdx.x;
    const int nwg = gX * gY * gridDim.z;
    if ((nwg & 7) == 0) idx = (idx & 7) * (nwg >> 3) + (idx >> 3);
    const int bx = idx % gX;
    const int tmpi = idx / gX;
    const int by = tmpi % gY;
    const int z  = tmpi / gY;

    const int bz = z >> 3, hz = z & 7;
    const bf16* Ab = A  + (size_t)bz * sAb + (size_t)hz * sAh;
    const bf16* Bb = Bt + (size_t)bz * sBb + (size_t)hz * sBh;
    const size_t offC = (size_t)bz * sCb + (size_t)hz * sCh;

    const int n0 = bx * 128;
    const int m0 = by * 256;

    const int t  = threadIdx.x;
    const int w  = t >> 6, l = t & 63;
    const int wr = w >> 1, wc = w & 1;              // wave grid 2x1 -> 128x64 each
    const int R0 = wr * 128, C0 = wc * 64;
    const int ml = l & 15, quad = l >> 4;           // MFMA fragment lanes

    // staging: 16B/lane; 4 lanes cover one 64-B row; 16 rows per chunk.
    // A: chunks w*4+i (i<4) -> rows 0..255; B: chunks w*2+i (i<2) -> rows 0..127.
    const int srow = l >> 2, sslot = l & 3;
    const bf16* pa[4];
    const bf16* pb[2];
    #pragma unroll
    for (int i = 0; i < 4; ++i) {
        const int r = (w * 4 + i) * 16 + srow;
        const int jj = sslot ^ ((r >> 1) & 3);
        pa[i] = Ab + (size_t)(m0 + r) * lda + jj * 8;
    }
    #pragma unroll
    for (int i = 0; i < 2; ++i) {
        const int r = (w * 2 + i) * 16 + srow;
        const int jj = sslot ^ ((r >> 1) & 3);
        pb[i] = Bb + (size_t)(n0 + r) * ldb + jj * 8;
    }

    fx4 acc[8][4];
    const fx4 zero = {0.f, 0.f, 0.f, 0.f};
    #pragma unroll
    for (int i = 0; i < 8; ++i)
        #pragma unroll
        for (int j = 0; j < 4; ++j) acc[i][j] = zero;

    const int nt = K >> 5;   // K-tiles of 32 (16 or 128 here; nt >= 2)

    // ---- prologue: stage tiles 0,1 (6 loads each); wait tile 0 ----
    ISSUE_TILE6(0, 0);
    ISSUE_TILE6(1, 1);
    asm volatile("s_waitcnt vmcnt(6)" ::: "memory");   // tile 0's 6 landed
    asm volatile("s_barrier" ::: "memory");

    for (int tt = 0; tt < nt; ++tt) {
        const int b = tt & 1;
        const bf16* sA = sm + b * 12288;
        const bf16* sB = sA + 8192;

        bf16x8 aF[4], b0[2], b1[2];

        // ---- X0: read A0 (4) + B0 (2) ----
        #pragma unroll
        for (int im = 0; im < 4; ++im)
            LDS_FRAG32(aF[im], sA, R0 + im * 16 + ml);
        #pragma unroll
        for (int in = 0; in < 2; ++in)
            LDS_FRAG32(b0[in], sB, C0 + in * 16 + ml);

        // ---- X1: P00 -> acc[0..3][0..1] | tail: read B1 ----
        __builtin_amdgcn_s_setprio(1);
        #pragma unroll
        for (int im = 0; im < 4; ++im)
            #pragma unroll
            for (int in = 0; in < 2; ++in)
                acc[im][in] = __builtin_amdgcn_mfma_f32_16x16x32_bf16(
                    aF[im], b0[in], acc[im][in], 0, 0, 0);
        __builtin_amdgcn_s_setprio(0);
        #pragma unroll
        for (int in = 0; in < 2; ++in)
            LDS_FRAG32(b1[in], sB, C0 + 32 + in * 16 + ml);

        // ---- X2: P01 -> acc[0..3][2..3] | tail: read A1 into aF (WAR) ----
        __builtin_amdgcn_s_setprio(1);
        #pragma unroll
        for (int im = 0; im < 4; ++im)
            #pragma unroll
            for (int in = 0; in < 2; ++in)
                acc[im][2 + in] = __builtin_amdgcn_mfma_f32_16x16x32_bf16(
                    aF[im], b1[in], acc[im][2 + in], 0, 0, 0);
        __builtin_amdgcn_s_setprio(0);
        #pragma unroll
        for (int im = 0; im < 4; ++im)
            LDS_FRAG32(aF[im], sA, R0 + 64 + im * 16 + ml);

        // ---- boundary: buf b read-complete -> refill; confirm tile t+1 ----
        asm volatile("s_barrier" ::: "memory");        // all buf-b reads done
        if (tt + 2 < nt) {
            ISSUE_TILE6(tt + 2, b);
            asm volatile("s_waitcnt vmcnt(6)" ::: "memory");  // t+1 landed; t+2 in flight
        } else if (tt + 1 < nt) {
            asm volatile("s_waitcnt vmcnt(0)" ::: "memory");  // epilogue drain
        }
        asm volatile("s_barrier" ::: "memory");        // t+1 landed for ALL waves

        // ---- X3: P11 -> acc[4..7][2..3] ----
        __builtin_amdgcn_s_setprio(1);
        #pragma unroll
        for (int im = 0; im < 4; ++im)
            #pragma unroll
            for (int in = 0; in < 2; ++in)
                acc[4 + im][2 + in] = __builtin_amdgcn_mfma_f32_16x16x32_bf16(
                    aF[im], b1[in], acc[4 + im][2 + in], 0, 0, 0);
        __builtin_amdgcn_s_setprio(0);

        // ---- X4: P10 -> acc[4..7][0..1] ----
        __builtin_amdgcn_s_setprio(1);
        #pragma unroll
        for (int im = 0; im < 4; ++im)
            #pragma unroll
            for (int in = 0; in < 2; ++in)
                acc[4 + im][in] = __builtin_amdgcn_mfma_f32_16x16x32_bf16(
                    aF[im], b0[in], acc[4 + im][in], 0, 0, 0);
        __builtin_amdgcn_s_setprio(0);
    }

    // ---- epilogue: C/D layout col=lane&15, row=(lane>>4)*4+reg ----
    #pragma unroll
    for (int ni = 0; ni < 4; ++ni) {
        const int cg = n0 + C0 + ni * 16 + ml;
        const float bv = biasv ? (bias32 ? ((const float*)biasv)[cg] : (float)((const bf16*)biasv)[cg]) : 0.f;
        #pragma unroll
        for (int mi = 0; mi < 8; ++mi) {
            const int rg = m0 + R0 + mi * 16 + quad * 4;
            #pragma unroll
            for (int r = 0; r < 4; ++r) {
                const float val = acc[mi][ni][r] * alpha + bv;
                const size_t idx = offC + (size_t)(rg + r) * ldc + cg;
                if (c32) ((float*)Cv)[idx] = val;
                else     ((bf16*)Cv)[idx] = (bf16)val;
            }
        }
    }
}

// In-place row softmax, rows of exactly 512 bf16. One wave per row (8 elems/lane).
__global__ __launch_bounds__(256) void softmax512(bf16* __restrict__ buf)
{
    const int row = blockIdx.x * 4 + (threadIdx.x >> 6);
    const int l = threadIdx.x & 63;
    bf16* p = buf + (size_t)row * 512 + l * 8;
    bf16x8 v = *(const bf16x8*)p;
    float f[8];
    float mx = -1e30f;
    #pragma unroll
    for (int j = 0; j < 8; ++j) {
        f[j] = (float)v[j];
        if (!(fabsf(f[j]) < 1e30f)) f[j] = -1e9f;   // NaN/Inf guard
        mx = fmaxf(mx, f[j]);
    }
    #pragma unroll
    for (int s = 1; s < 64; s <<= 1) mx = fmaxf(mx, __shfl_xor(mx, s));
    float sum = 0.f;
    #pragma unroll
    for (int j = 0; j < 8; ++j) { f[j] = __expf(f[j] - mx); sum += f[j]; }
    #pragma unroll
    for (int s = 1; s < 64; s <<= 1) sum += __shfl_xor(sum, s);
    const float inv = 1.f / sum;
    #pragma unroll
    for (int j = 0; j < 8; ++j) v[j] = (bf16)(f[j] * inv);
    *(bf16x8*)p = v;
}

// out[z][d][s] = in[b][s][h*512+d], z = b*8+h. 32x32 tiles via LDS. (internal bf16)
__global__ __launch_bounds__(256) void transpose_heads(
    const bf16* __restrict__ in, bf16* __restrict__ out)
{
    __shared__ bf16 tile[32][33];
    const int z = blockIdx.z, b = z >> 3, h = z & 7;
    const int s0 = blockIdx.x * 32, d0 = blockIdx.y * 32;
    const int tx = threadIdx.x, ty = threadIdx.y;   // 32 x 8
    #pragma unroll
    for (int j = 0; j < 4; ++j) {
        const int s = s0 + ty + j * 8;
        tile[ty + j * 8][tx] = in[(size_t)b * SK_ * DM_ + (size_t)s * DM_ + h * DK_ + d0 + tx];
    }
    __syncthreads();
    #pragma unroll
    for (int j = 0; j < 4; ++j) {
        const int d = d0 + ty + j * 8;
        out[(size_t)z * DK_ * SK_ + (size_t)d * SK_ + s0 + tx] = tile[tx][ty + j * 8];
    }
}

extern "C" void kernel_launch(void* const* d_in, const int* in_sizes, int n_in,
                              void* d_out, int out_size, void* d_ws, size_t ws_size,
                              hipStream_t stream)
{
    const void* query = d_in[0];
    const void* key   = d_in[1];
    const void* value = d_in[2];
    const void* imf   = d_in[3];
    const void* W0 = d_in[4];  const void* b0 = d_in[5];
    const void* W1 = d_in[6];  const void* b1 = d_in[7];
    const void* W2 = d_in[8];  const void* b2 = d_in[9];
    const void* W3 = d_in[10]; const void* b3 = d_in[11];

    // ---- workspace layout (bf16 elems; 16B flag header), ~96 MB ----
    bf16* ws    = (bf16*)d_ws;
    int*  flagp = (int*)d_ws;
    bf16* wslot = ws + 8;                    // 16777216: one bf16 weight at a time
    bf16* R     = ws + 8 + 16777216;         // 33554432-elem multi-use region
    bf16* inbuf = R;                         //   8388608: k/v/imf bf16, serially
    bf16* vproj = R + 8388608;               //   8388608 (dead after transpose)
    bf16* imfp  = R + 16777216;              //   8388608 (dead after transpose)
    bf16* s1    = R;                         //  33554432 (after inbuf/vproj/imfp die)
    bf16* xcat  = R;                         //  overlays s1 (dead after p@imf GEMM)

    // ---- d_out (134 MB) multi-duty until the final GEMM rewrites it all ----
    bf16* obase = (bf16*)d_out;
    bf16* qproj = obase;                     // 33554432 (dead after scores GEMM)
    bf16* qbf   = obase + 33554432;          // 33554432 (dead after qproj GEMM)
    bf16* kproj = obase + 33554432;          //  8388608 (lives where qbf died)
    bf16* vT    = obase + 41943040;          //  8388608
    bf16* imfT  = obase + 50331648;          //  8388608
    bf16* s2    = obase;                     // 33554432 (lives where qproj died)

    const float inv_sqrt_dk = 0.04419417382415922f;  // 1/sqrt(512)

    // 0: decide external dtype (fp32 vs bf16) from query's bit patterns
    sniff_dtype<<<1, 64, 0, stream>>>((const uint32_t*)query, flagp);

    // ---- Q path: convert, project (256x128 pipelined: 32x32 = 1024 WGs) ----
    cvt_to_bf16<<<16384, 256, 0, stream>>>(query, qbf, flagp);
    cvt_to_bf16<<<8192, 256, 0, stream>>>(W0, wslot, flagp);
    gemm_pipe<<<dim3(32, 32, 1), 256, 0, stream>>>(qbf, wslot, qproj, b0,
        4096, 4096, 4096, 4096, 1.f, 0,0,0,0,0,0, flagp, 1);
    // ---- K path (128^2 kernel: proven on M=2048 projections) ----
    cvt_to_bf16<<<4096, 256, 0, stream>>>(key, inbuf, flagp);
    cvt_to_bf16<<<8192, 256, 0, stream>>>(W1, wslot, flagp);
    gemm_bt<<<dim3(32, 16, 1), 256, 0, stream>>>(inbuf, wslot, kproj, b1,
        4096, 4096, 4096, 4096, 1.f, 0,0,0,0,0,0, flagp, 1);
    // ---- V path ----
    cvt_to_bf16<<<4096, 256, 0, stream>>>(value, inbuf, flagp);
    cvt_to_bf16<<<8192, 256, 0, stream>>>(W2, wslot, flagp);
    gemm_bt<<<dim3(32, 16, 1), 256, 0, stream>>>(inbuf, wslot, vproj, b2,
        4096, 4096, 4096, 4096, 1.f, 0,0,0,0,0,0, flagp, 1);
    // ---- imf path ----
    cvt_to_bf16<<<4096, 256, 0, stream>>>(imf, inbuf, flagp);
    cvt_to_bf16<<<8192, 256, 0, stream>>>(W3, wslot, flagp);
    gemm_bt<<<dim3(32, 16, 1), 256, 0, stream>>>(inbuf, wslot, imfp, b3,
        4096, 4096, 4096, 4096, 1.f, 0,0,0,0,0,0, flagp, 1);

    // ---- per-head transposes so the @imf and @v einsums become A·B^T ----
    transpose_heads<<<dim3(16, 16, 32), dim3(32, 8), 0, stream>>>(vproj, vT);
    transpose_heads<<<dim3(16, 16, 32), dim3(32, 8), 0, stream>>>(imfp, imfT);

    // ---- scores = q·k^T / sqrt(dk)  (4x8x32 = 1024 WGs) ----
    gemm_pipe<<<dim3(4, 8, 32), 256, 0, stream>>>(qproj, kproj, s1, nullptr,
        512, 4096, 4096, 512, inv_sqrt_dk,
        (long long)SQ_*DM_, (long long)DK_, (long long)SK_*DM_, (long long)DK_,
        (long long)H_*SQ_*SK_, (long long)SQ_*SK_, flagp, 0);
    softmax512<<<dim3(16384), 256, 0, stream>>>(s1);
    // ---- s2 = p @ imf_h (overwrites dead qproj in d_out) ----
    gemm_pipe<<<dim3(4, 8, 32), 256, 0, stream>>>(s1, imfT, s2, nullptr,
        512, 512, 512, 512, 1.f,
        (long long)H_*SQ_*SK_, (long long)SQ_*SK_, (long long)H_*DK_*SK_, (long long)DK_*SK_,
        (long long)H_*SQ_*SK_, (long long)SQ_*SK_, flagp, 0);
    softmax512<<<dim3(16384), 256, 0, stream>>>(s2);
    // ---- x = im_attn @ v_h -> concat-head layout (xcat overlays dead s1) ----
    gemm_pipe<<<dim3(4, 8, 32), 256, 0, stream>>>(s2, vT, xcat, nullptr,
        512, 512, 512, 4096, 1.f,
        (long long)H_*SQ_*SK_, (long long)SQ_*SK_, (long long)H_*DK_*SK_, (long long)DK_*SK_,
        (long long)SQ_*DM_, (long long)DK_, flagp, 0);
    // ---- out = xcat @ W3^T + b3 (re-convert shared W3; fp32 store per flag) ----
    cvt_to_bf16<<<8192, 256, 0, stream>>>(W3, wslot, flagp);
    gemm_pipe<<<dim3(32, 32, 1), 256, 0, stream>>>(xcat, wslot, d_out, b3,
        4096, 4096, 4096, 4096, 1.f, 0,0,0,0,0,0, flagp, 3);
}

// Round 9
// 1503.337 us; speedup vs baseline: 1.1405x; 1.1405x over previous
//
#include <hip/hip_runtime.h>
#include <hip/hip_bf16.h>
#include <stdint.h>

// Problem constants (fixed by the reference)
#define B_   4
#define H_   8
#define SQ_  2048
#define SK_  512
#define DM_  4096
#define DK_  512

typedef __bf16 bf16;
typedef __bf16 bf16x8 __attribute__((ext_vector_type(8)));
typedef float  fx4    __attribute__((ext_vector_type(4)));

// address-space-qualified pointer types for global_load_lds
typedef __attribute__((address_space(1))) void gv_t;   // global
typedef __attribute__((address_space(3))) void lv_t;   // LDS

// ---------------------------------------------------------------------------
// Dtype sniffer (unchanged). flag=1 -> external tensors are fp32.
__global__ void sniff_dtype(const uint32_t* __restrict__ q, int* __restrict__ flag)
{
    const int l = threadIdx.x;  // 64 lanes
    int cnt = 0;
    #pragma unroll
    for (int i = 0; i < 4; ++i) {
        const uint32_t u = q[l * 4 + i];
        const int e = (u >> 7) & 0xFF;
        cnt += (e >= 100 && e <= 135) ? 1 : 0;
    }
    #pragma unroll
    for (int s = 1; s < 64; s <<= 1) cnt += __shfl_xor(cnt, s);
    if (l == 0) *flag = (cnt < 150) ? 1 : 0;
}

// ---------------------------------------------------------------------------
// One-time dtype normalization: fp32 -> bf16 (or bf16 passthrough copy).
__global__ __launch_bounds__(256) void cvt_to_bf16(
    const void* __restrict__ in, bf16* __restrict__ out, const int* __restrict__ flagp)
{
    const size_t i = ((size_t)blockIdx.x * 256 + threadIdx.x) * 8;
    if (*flagp) {
        const float4* p = (const float4*)((const float*)in + i);
        const float4 u0 = p[0], u1 = p[1];
        bf16x8 v;
        v[0] = (bf16)u0.x; v[1] = (bf16)u0.y; v[2] = (bf16)u0.z; v[3] = (bf16)u0.w;
        v[4] = (bf16)u1.x; v[5] = (bf16)u1.y; v[6] = (bf16)u1.z; v[7] = (bf16)u1.w;
        *(bf16x8*)(out + i) = v;
    } else {
        *(bf16x8*)(out + i) = *(const bf16x8*)((const bf16*)in + i);
    }
}

// ---------------------------------------------------------------------------
// 128^2-tile GEMM (verified rounds 0-1). Kept for the three M=2048 projections.
__global__ __launch_bounds__(256, 3) void gemm_bt(
    const bf16* __restrict__ A, const bf16* __restrict__ Bt,
    void* __restrict__ Cv, const void* __restrict__ biasv,
    int K, int lda, int ldb, int ldc, float alpha,
    long long sAb, long long sAh, long long sBb, long long sBh,
    long long sCb, long long sCh,
    const int* __restrict__ flagp, int ebits)
{
    __shared__ bf16 sA[128 * 64];
    __shared__ bf16 sB[128 * 64];

    const int fl = ebits ? *flagp : 0;
    const bool bias32 = fl && (ebits & 1);
    const bool c32    = fl && (ebits & 2);

    const int z = blockIdx.z;
    const int bz = z >> 3, hz = z & 7;
    const bf16* Ab = A  + (size_t)bz * sAb + (size_t)hz * sAh;
    const bf16* Bb = Bt + (size_t)bz * sBb + (size_t)hz * sBh;
    const size_t offC = (size_t)bz * sCb + (size_t)hz * sCh;

    const int n0 = blockIdx.x * 128;
    const int m0 = blockIdx.y * 128;

    const int t = threadIdx.x;
    const int w = t >> 6, l = t & 63;
    const int lrow = l >> 3, lcol = l & 7;
    const int wm = (w >> 1) * 64, wn = (w & 1) * 64;
    const int ml = l & 15, quad = l >> 4;

    const bf16* pa[4];
    const bf16* pb[4];
    #pragma unroll
    for (int i = 0; i < 4; ++i) {
        const int c = w * 4 + i;
        const int r = c * 8 + lrow;
        const int jj = lcol ^ (r & 7);
        pa[i] = Ab + (size_t)(m0 + r) * lda + jj * 8;
        pb[i] = Bb + (size_t)(n0 + r) * ldb + jj * 8;
    }

    fx4 acc[4][4];
    const fx4 zero = {0.f, 0.f, 0.f, 0.f};
    #pragma unroll
    for (int i = 0; i < 4; ++i)
        #pragma unroll
        for (int j = 0; j < 4; ++j) acc[i][j] = zero;

    for (int kt = 0; kt < K; kt += 64) {
        #pragma unroll
        for (int i = 0; i < 4; ++i) {
            const int c = w * 4 + i;
            __builtin_amdgcn_global_load_lds((gv_t*)(pa[i] + kt), (lv_t*)(sA + c * 512), 16, 0, 0);
            __builtin_amdgcn_global_load_lds((gv_t*)(pb[i] + kt), (lv_t*)(sB + c * 512), 16, 0, 0);
        }
        __syncthreads();

        #pragma unroll
        for (int kk = 0; kk < 64; kk += 32) {
            bf16x8 af[4], bfr[4];
            const int jbase = (kk >> 3) + quad;
            #pragma unroll
            for (int mi = 0; mi < 4; ++mi) {
                const int r = wm + mi * 16 + ml;
                af[mi] = *(const bf16x8*)&sA[r * 64 + ((jbase ^ (r & 7)) << 3)];
            }
            #pragma unroll
            for (int ni = 0; ni < 4; ++ni) {
                const int r = wn + ni * 16 + ml;
                bfr[ni] = *(const bf16x8*)&sB[r * 64 + ((jbase ^ (r & 7)) << 3)];
            }
            #pragma unroll
            for (int mi = 0; mi < 4; ++mi)
                #pragma unroll
                for (int ni = 0; ni < 4; ++ni)
                    acc[mi][ni] = __builtin_amdgcn_mfma_f32_16x16x32_bf16(
                        af[mi], bfr[ni], acc[mi][ni], 0, 0, 0);
        }
        __syncthreads();
    }

    #pragma unroll
    for (int ni = 0; ni < 4; ++ni) {
        const int cg = n0 + wn + ni * 16 + ml;
        const float bv = biasv ? (bias32 ? ((const float*)biasv)[cg] : (float)((const bf16*)biasv)[cg]) : 0.f;
        #pragma unroll
        for (int mi = 0; mi < 4; ++mi) {
            const int rg = m0 + wm + mi * 16 + quad * 4;
            #pragma unroll
            for (int r = 0; r < 4; ++r) {
                const float val = acc[mi][ni][r] * alpha + bv;
                const size_t idx = offC + (size_t)(rg + r) * ldc + cg;
                if (c32) ((float*)Cv)[idx] = val;
                else     ((bf16*)Cv)[idx] = (bf16)val;
            }
        }
    }
}

// ---------------------------------------------------------------------------
// 256^2 8-phase GEMM, round 7/8/9: FAITHFUL per-phase staging interleave (the
// m196-isolated lever rounds 3-6 omitted). 512 thr = 8 waves (2x4), per-wave
// C 128x64, BK=64, 2-buf LDS 128 KiB, 1 WG/CU.
// Per K-tile (half-iteration, 4 phases), consuming buf cb and staging tile ts
// into the OTHER buffer sb (dead since its last read 1 half-iteration ago):
//   P1: read A0(8)+B0(4) | stage ts A-halves(4 ld) | bar;lgkm0;SB0;prio;16 MFMA;prio;bar
//   P2: read B1(4)       | stage ts Bh0(2)         | ...16 MFMA...
//   P3: read A1(8)       | stage ts Bh1(2)         | ...16 MFMA...
//   P4: 16 MFMA (a,b0 held in regs) ; vmcnt(0) ; bar
// The vmcnt(0) at P4 drains loads issued >=2 phases (~1200cyc > HBM ~900cyc)
// earlier -> ~free; buffer handoff needs full drain so counted-N is unneeded.
// ds_reads are plain C++ loads (compiler emits its own lgkm before MFMA use:
// correct even if asm waits are ignored); sched_barrier(0) pins MFMAs after
// the barrier+wait (rule 18). Barriers uniform across waves (dostage uniform).
#define BARRIER   asm volatile("s_barrier" ::: "memory")
#define LGKM0     asm volatile("s_waitcnt lgkmcnt(0)" ::: "memory")
#define VM0       asm volatile("s_waitcnt vmcnt(0)" ::: "memory")
#define SCHED0    __builtin_amdgcn_sched_barrier(0)

// fragment load: row fr, k-group j=kI*4+quad, XOR slot swizzle (verified 0-conflict)
#define LDS_FRAG(dst, base, fr, kI)                                               \
    dst = *(const bf16x8*)&base[(fr) * 64 + ((((kI) * 4 + quad) ^ ((fr) & 7)) << 3)]

#define READ_A(dst, sX, roff)                                                     \
    _Pragma("unroll")                                                             \
    for (int im_ = 0; im_ < 4; ++im_)                                             \
        _Pragma("unroll")                                                         \
        for (int kI_ = 0; kI_ < 2; ++kI_)                                         \
            LDS_FRAG(dst[im_][kI_], sX, R0 + (roff) + im_ * 16 + ml, kI_);

#define READ_B(dst, sX, coff)                                                     \
    _Pragma("unroll")                                                             \
    for (int in_ = 0; in_ < 2; ++in_)                                             \
        _Pragma("unroll")                                                         \
        for (int kI_ = 0; kI_ < 2; ++kI_)                                         \
            LDS_FRAG(dst[in_][kI_], sX, C0 + (coff) + in_ * 16 + ml, kI_);

#define MFMA_Q(mo, no, afr_, bfr_)                                                \
    __builtin_amdgcn_s_setprio(1);                                                \
    _Pragma("unroll")                                                             \
    for (int kI_ = 0; kI_ < 2; ++kI_)                                             \
        _Pragma("unroll")                                                         \
        for (int im_ = 0; im_ < 4; ++im_)                                         \
            _Pragma("unroll")                                                     \
            for (int in_ = 0; in_ < 2; ++in_)                                     \
                acc[(mo) + im_][(no) + in_] =                                     \
                    __builtin_amdgcn_mfma_f32_16x16x32_bf16(                      \
                        afr_[im_][kI_], bfr_[in_][kI_],                           \
                        acc[(mo) + im_][(no) + in_], 0, 0, 0);                    \
    __builtin_amdgcn_s_setprio(0);

// stage both A-halves of tile ts into buffer sb (4 x 16B loads/thread)
#define STAGE_A(ts, sb)                                                           \
    do {                                                                          \
        _Pragma("unroll")                                                         \
        for (int h_ = 0; h_ < 2; ++h_)                                            \
            _Pragma("unroll")                                                     \
            for (int j_ = 0; j_ < 2; ++j_)                                        \
                __builtin_amdgcn_global_load_lds(                                 \
                    (gv_t*)(pA[h_][j_] + (size_t)(ts) * 64),                      \
                    (lv_t*)(&sm[sb][0][h_ * 8192 + (2 * w + j_) * 512]),          \
                    16, 0, 0);                                                    \
    } while (0)

// stage one B-half h of tile ts into buffer sb (2 x 16B loads/thread)
#define STAGE_B(ts, sb, h)                                                        \
    do {                                                                          \
        _Pragma("unroll")                                                         \
        for (int j_ = 0; j_ < 2; ++j_)                                            \
            __builtin_amdgcn_global_load_lds(                                     \
                (gv_t*)(pB[h][j_] + (size_t)(ts) * 64),                           \
                (lv_t*)(&sm[sb][1][(h) * 8192 + (2 * w + j_) * 512]),             \
                16, 0, 0);                                                        \
    } while (0)

#define HALF_ITER(cb, ts, sb, dostage)                                            \
    do {                                                                          \
        const bf16* sA_ = &sm[cb][0][0];                                          \
        const bf16* sB_ = &sm[cb][1][0];                                          \
        /* P1 */                                                                  \
        READ_A(afr, sA_, 0);                                                      \
        READ_B(b0r, sB_, 0);                                                      \
        if (dostage) { STAGE_A(ts, sb); }                                         \
        BARRIER; LGKM0; SCHED0;                                                   \
        MFMA_Q(0, 0, afr, b0r);                                                   \
        BARRIER;                                                                  \
        /* P2 */                                                                  \
        READ_B(b1r, sB_, 32);                                                     \
        if (dostage) { STAGE_B(ts, sb, 0); }                                      \
        BARRIER; LGKM0; SCHED0;                                                   \
        MFMA_Q(0, 2, afr, b1r);                                                   \
        BARRIER;                                                                  \
        /* P3 */                                                                  \
        READ_A(afr, sA_, 64);                                                     \
        if (dostage) { STAGE_B(ts, sb, 1); }                                      \
        BARRIER; LGKM0; SCHED0;                                                   \
        MFMA_Q(4, 2, afr, b1r);                                                   \
        BARRIER;                                                                  \
        /* P4: pure MFMA; drain staged DMA; buffer handoff */                     \
        MFMA_Q(4, 0, afr, b0r);                                                   \
        VM0;                                                                      \
        BARRIER;                                                                  \
    } while (0)

__global__ __launch_bounds__(512, 2) void gemm256(
    const bf16* __restrict__ A, const bf16* __restrict__ Bt,
    void* __restrict__ Cv, const void* __restrict__ biasv,
    int K, int lda, int ldb, int ldc, float alpha,
    long long sAb, long long sAh, long long sBb, long long sBh,
    long long sCb, long long sCh,
    const int* __restrict__ flagp, int ebits)
{
    __shared__ bf16 sm[2][2][256 * 64];   // [buf][A/B][tile] = 128 KiB

    const int fl = ebits ? *flagp : 0;
    const bool bias32 = fl && (ebits & 1);
    const bool c32    = fl && (ebits & 2);

    // ---- XCD-bijective block swizzle (all grids here are %8==0) ----
    const int gX = gridDim.x, gY = gridDim.y;
    int idx = (blockIdx.z * gY + blockIdx.y) * gX + blockIdx.x;
    const int nwg = gX * gY * gridDim.z;
    if ((nwg & 7) == 0) idx = (idx & 7) * (nwg >> 3) + (idx >> 3);
    const int bx = idx % gX;
    const int tmpi = idx / gX;
    const int by = tmpi % gY;
    const int z  = tmpi / gY;

    const int bz = z >> 3, hz = z & 7;
    const bf16* Ab = A  + (size_t)bz * sAb + (size_t)hz * sAh;
    const bf16* Bb = Bt + (size_t)bz * sBb + (size_t)hz * sBh;
    const size_t offC = (size_t)bz * sCb + (size_t)hz * sCh;

    const int n0 = bx * 256;
    const int m0 = by * 256;

    const int t  = threadIdx.x;
    const int w  = t >> 6, l = t & 63;
    const int lrow = l >> 3, lcol = l & 7;          // staging decomposition
    const int wr = w >> 2, wc = w & 3;              // wave grid 2x4
    const int R0 = wr * 128, C0 = wc * 64;          // per-wave C sub-tile
    const int ml = l & 15, quad = l >> 4;           // MFMA fragment lanes

    // staging pointers: half h (128 rows), load j -> chunk 2w+j of that half
    // (chunk = 8 rows x 64 cols = 512 elems; lane covers row lrow, slot lcol
    //  with the XOR involution pre-applied to the GLOBAL column group)
    const bf16* pA[2][2];
    const bf16* pB[2][2];
    #pragma unroll
    for (int h = 0; h < 2; ++h)
        #pragma unroll
        for (int j = 0; j < 2; ++j) {
            const int r = h * 128 + (2 * w + j) * 8 + lrow;
            const int jj = lcol ^ (r & 7);
            pA[h][j] = Ab + (size_t)(m0 + r) * lda + jj * 8;
            pB[h][j] = Bb + (size_t)(n0 + r) * ldb + jj * 8;
        }

    fx4 acc[8][4];
    const fx4 zero = {0.f, 0.f, 0.f, 0.f};
    #pragma unroll
    for (int i = 0; i < 8; ++i)
        #pragma unroll
        for (int j = 0; j < 4; ++j) acc[i][j] = zero;

    bf16x8 afr[4][2], b0r[2][2], b1r[2][2];

    const int nt  = K >> 6;    // K-tiles of 64 (8 or 64 here -> always even)
    const int nit = nt >> 1;   // iterations of 2 K-tiles

    // ---- prologue: stage tile 0 -> buf0 fully; drain; sync ----
    STAGE_A(0, 0);
    STAGE_B(0, 0, 0);
    STAGE_B(0, 0, 1);
    VM0;
    BARRIER;

    for (int it = 0; it < nit; ++it) {
        // consume tile 2it (buf0); stage tile 2it+1 -> buf1 (consumed next half)
        HALF_ITER(0, 2 * it + 1, 1, true);
        // consume tile 2it+1 (buf1); stage tile 2it+2 -> buf0 (next iteration)
        HALF_ITER(1, 2 * it + 2, 0, (it + 1 < nit));
    }

    // ---- epilogue: C/D layout col=lane&15, row=(lane>>4)*4+reg ----
    #pragma unroll
    for (int ni = 0; ni < 4; ++ni) {
        const int cg = n0 + C0 + ni * 16 + ml;
        const float bv = biasv ? (bias32 ? ((const float*)biasv)[cg] : (float)((const bf16*)biasv)[cg]) : 0.f;
        #pragma unroll
        for (int mi = 0; mi < 8; ++mi) {
            const int rg = m0 + R0 + mi * 16 + quad * 4;
            #pragma unroll
            for (int r = 0; r < 4; ++r) {
                const float val = acc[mi][ni][r] * alpha + bv;
                const size_t idx = offC + (size_t)(rg + r) * ldc + cg;
                if (c32) ((float*)Cv)[idx] = val;
                else     ((bf16*)Cv)[idx] = (bf16)val;
            }
        }
    }
}

// In-place row softmax, rows of exactly 512 bf16. One wave per row (8 elems/lane).
__global__ __launch_bounds__(256) void softmax512(bf16* __restrict__ buf)
{
    const int row = blockIdx.x * 4 + (threadIdx.x >> 6);
    const int l = threadIdx.x & 63;
    bf16* p = buf + (size_t)row * 512 + l * 8;
    bf16x8 v = *(const bf16x8*)p;
    float f[8];
    float mx = -1e30f;
    #pragma unroll
    for (int j = 0; j < 8; ++j) {
        f[j] = (float)v[j];
        if (!(fabsf(f[j]) < 1e30f)) f[j] = -1e9f;   // NaN/Inf guard
        mx = fmaxf(mx, f[j]);
    }
    #pragma unroll
    for (int s = 1; s < 64; s <<= 1) mx = fmaxf(mx, __shfl_xor(mx, s));
    float sum = 0.f;
    #pragma unroll
    for (int j = 0; j < 8; ++j) { f[j] = __expf(f[j] - mx); sum += f[j]; }
    #pragma unroll
    for (int s = 1; s < 64; s <<= 1) sum += __shfl_xor(sum, s);
    const float inv = 1.f / sum;
    #pragma unroll
    for (int j = 0; j < 8; ++j) v[j] = (bf16)(f[j] * inv);
    *(bf16x8*)p = v;
}

// out[z][d][s] = in[b][s][h*512+d], z = b*8+h. 32x32 tiles via LDS. (internal bf16)
__global__ __launch_bounds__(256) void transpose_heads(
    const bf16* __restrict__ in, bf16* __restrict__ out)
{
    __shared__ bf16 tile[32][33];
    const int z = blockIdx.z, b = z >> 3, h = z & 7;
    const int s0 = blockIdx.x * 32, d0 = blockIdx.y * 32;
    const int tx = threadIdx.x, ty = threadIdx.y;   // 32 x 8
    #pragma unroll
    for (int j = 0; j < 4; ++j) {
        const int s = s0 + ty + j * 8;
        tile[ty + j * 8][tx] = in[(size_t)b * SK_ * DM_ + (size_t)s * DM_ + h * DK_ + d0 + tx];
    }
    __syncthreads();
    #pragma unroll
    for (int j = 0; j < 4; ++j) {
        const int d = d0 + ty + j * 8;
        out[(size_t)z * DK_ * SK_ + (size_t)d * SK_ + s0 + tx] = tile[tx][ty + j * 8];
    }
}

extern "C" void kernel_launch(void* const* d_in, const int* in_sizes, int n_in,
                              void* d_out, int out_size, void* d_ws, size_t ws_size,
                              hipStream_t stream)
{
    const void* query = d_in[0];
    const void* key   = d_in[1];
    const void* value = d_in[2];
    const void* imf   = d_in[3];
    const void* W0 = d_in[4];  const void* b0 = d_in[5];
    const void* W1 = d_in[6];  const void* b1 = d_in[7];
    const void* W2 = d_in[8];  const void* b2 = d_in[9];
    const void* W3 = d_in[10]; const void* b3 = d_in[11];

    // ---- workspace layout (bf16 elems; 16B flag header), ~96 MB ----
    bf16* ws    = (bf16*)d_ws;
    int*  flagp = (int*)d_ws;
    bf16* wslot = ws + 8;                    // 16777216: one bf16 weight at a time
    bf16* R     = ws + 8 + 16777216;         // 33554432-elem multi-use region
    bf16* inbuf = R;                         //   8388608: k/v/imf bf16, serially
    bf16* vproj = R + 8388608;               //   8388608 (dead after transpose)
    bf16* imfp  = R + 16777216;              //   8388608 (dead after transpose)
    bf16* s1    = R;                         //  33554432 (after inbuf/vproj/imfp die)
    bf16* xcat  = R;                         //  overlays s1 (dead after p@imf GEMM)

    // ---- d_out (134 MB) multi-duty until the final GEMM rewrites it all ----
    bf16* obase = (bf16*)d_out;
    bf16* qproj = obase;                     // 33554432 (dead after scores GEMM)
    bf16* qbf   = obase + 33554432;          // 33554432 (dead after qproj GEMM)
    bf16* kproj = obase + 33554432;          //  8388608 (lives where qbf died)
    bf16* vT    = obase + 41943040;          //  8388608
    bf16* imfT  = obase + 50331648;          //  8388608
    bf16* s2    = obase;                     // 33554432 (lives where qproj died)

    const float inv_sqrt_dk = 0.04419417382415922f;  // 1/sqrt(512)

    // 0: decide external dtype (fp32 vs bf16) from query's bit patterns
    sniff_dtype<<<1, 64, 0, stream>>>((const uint32_t*)query, flagp);

    // ---- Q path: convert, project (256^2 8-phase: 16x32 = 512 WGs) ----
    cvt_to_bf16<<<16384, 256, 0, stream>>>(query, qbf, flagp);
    cvt_to_bf16<<<8192, 256, 0, stream>>>(W0, wslot, flagp);
    gemm256<<<dim3(16, 32, 1), 512, 0, stream>>>(qbf, wslot, qproj, b0,
        4096, 4096, 4096, 4096, 1.f, 0,0,0,0,0,0, flagp, 1);
    // ---- K path (128^2 kernel: proven on M=2048 projections) ----
    cvt_to_bf16<<<4096, 256, 0, stream>>>(key, inbuf, flagp);
    cvt_to_bf16<<<8192, 256, 0, stream>>>(W1, wslot, flagp);
    gemm_bt<<<dim3(32, 16, 1), 256, 0, stream>>>(inbuf, wslot, kproj, b1,
        4096, 4096, 4096, 4096, 1.f, 0,0,0,0,0,0, flagp, 1);
    // ---- V path ----
    cvt_to_bf16<<<4096, 256, 0, stream>>>(value, inbuf, flagp);
    cvt_to_bf16<<<8192, 256, 0, stream>>>(W2, wslot, flagp);
    gemm_bt<<<dim3(32, 16, 1), 256, 0, stream>>>(inbuf, wslot, vproj, b2,
        4096, 4096, 4096, 4096, 1.f, 0,0,0,0,0,0, flagp, 1);
    // ---- imf path ----
    cvt_to_bf16<<<4096, 256, 0, stream>>>(imf, inbuf, flagp);
    cvt_to_bf16<<<8192, 256, 0, stream>>>(W3, wslot, flagp);
    gemm_bt<<<dim3(32, 16, 1), 256, 0, stream>>>(inbuf, wslot, imfp, b3,
        4096, 4096, 4096, 4096, 1.f, 0,0,0,0,0,0, flagp, 1);

    // ---- per-head transposes so the @imf and @v einsums become A·B^T ----
    transpose_heads<<<dim3(16, 16, 32), dim3(32, 8), 0, stream>>>(vproj, vT);
    transpose_heads<<<dim3(16, 16, 32), dim3(32, 8), 0, stream>>>(imfp, imfT);

    // ---- scores = q·k^T / sqrt(dk)  (2x8x32 = 512 WGs) ----
    gemm256<<<dim3(2, 8, 32), 512, 0, stream>>>(qproj, kproj, s1, nullptr,
        512, 4096, 4096, 512, inv_sqrt_dk,
        (long long)SQ_*DM_, (long long)DK_, (long long)SK_*DM_, (long long)DK_,
        (long long)H_*SQ_*SK_, (long long)SQ_*SK_, flagp, 0);
    softmax512<<<dim3(16384), 256, 0, stream>>>(s1);
    // ---- s2 = p @ imf_h (overwrites dead qproj in d_out) ----
    gemm256<<<dim3(2, 8, 32), 512, 0, stream>>>(s1, imfT, s2, nullptr,
        512, 512, 512, 512, 1.f,
        (long long)H_*SQ_*SK_, (long long)SQ_*SK_, (long long)H_*DK_*SK_, (long long)DK_*SK_,
        (long long)H_*SQ_*SK_, (long long)SQ_*SK_, flagp, 0);
    softmax512<<<dim3(16384), 256, 0, stream>>>(s2);
    // ---- x = im_attn @ v_h -> concat-head layout (xcat overlays dead s1) ----
    gemm256<<<dim3(2, 8, 32), 512, 0, stream>>>(s2, vT, xcat, nullptr,
        512, 512, 512, 4096, 1.f,
        (long long)H_*SQ_*SK_, (long long)SQ_*SK_, (long long)H_*DK_*SK_, (long long)DK_*SK_,
        (long long)SQ_*DM_, (long long)DK_, flagp, 0);
    // ---- out = xcat @ W3^T + b3 (re-convert shared W3; fp32 store per flag) ----
    cvt_to_bf16<<<8192, 256, 0, stream>>>(W3, wslot, flagp);
    gemm256<<<dim3(16, 32, 1), 512, 0, stream>>>(xcat, wslot, d_out, b3,
        4096, 4096, 4096, 4096, 1.f, 0,0,0,0,0,0, flagp, 3);
}

// Round 10
// 1454.419 us; speedup vs baseline: 1.1789x; 1.0336x over previous
//
#include <hip/hip_runtime.h>
#include <hip/hip_bf16.h>
#include <stdint.h>

// Problem constants (fixed by the reference)
#define B_   4
#define H_   8
#define SQ_  2048
#define SK_  512
#define DM_  4096
#define DK_  512

typedef __bf16 bf16;
typedef __bf16 bf16x8 __attribute__((ext_vector_type(8)));
typedef float  fx4    __attribute__((ext_vector_type(4)));

// address-space-qualified pointer types for global_load_lds
typedef __attribute__((address_space(1))) void gv_t;   // global
typedef __attribute__((address_space(3))) void lv_t;   // LDS

// ---------------------------------------------------------------------------
// Dtype sniffer (unchanged). flag=1 -> external tensors are fp32.
__global__ void sniff_dtype(const uint32_t* __restrict__ q, int* __restrict__ flag)
{
    const int l = threadIdx.x;  // 64 lanes
    int cnt = 0;
    #pragma unroll
    for (int i = 0; i < 4; ++i) {
        const uint32_t u = q[l * 4 + i];
        const int e = (u >> 7) & 0xFF;
        cnt += (e >= 100 && e <= 135) ? 1 : 0;
    }
    #pragma unroll
    for (int s = 1; s < 64; s <<= 1) cnt += __shfl_xor(cnt, s);
    if (l == 0) *flag = (cnt < 150) ? 1 : 0;
}

// ---------------------------------------------------------------------------
// One-time dtype normalization: fp32 -> bf16 (or bf16 passthrough copy).
__global__ __launch_bounds__(256) void cvt_to_bf16(
    const void* __restrict__ in, bf16* __restrict__ out, const int* __restrict__ flagp)
{
    const size_t i = ((size_t)blockIdx.x * 256 + threadIdx.x) * 8;
    if (*flagp) {
        const float4* p = (const float4*)((const float*)in + i);
        const float4 u0 = p[0], u1 = p[1];
        bf16x8 v;
        v[0] = (bf16)u0.x; v[1] = (bf16)u0.y; v[2] = (bf16)u0.z; v[3] = (bf16)u0.w;
        v[4] = (bf16)u1.x; v[5] = (bf16)u1.y; v[6] = (bf16)u1.z; v[7] = (bf16)u1.w;
        *(bf16x8*)(out + i) = v;
    } else {
        *(bf16x8*)(out + i) = *(const bf16x8*)((const bf16*)in + i);
    }
}

// ---------------------------------------------------------------------------
// Stage two bias vectors contiguously (dtype preserved, per sniffed flag) so
// a z-batched GEMM can index bias per z via bstride. 8192 elems, grid 32x256.
__global__ __launch_bounds__(256) void copy_bias2(
    const void* __restrict__ b1, const void* __restrict__ b2,
    void* __restrict__ dst, const int* __restrict__ flagp)
{
    const int i = blockIdx.x * 256 + threadIdx.x;   // 0..8191
    const void* src = (i < 4096) ? b1 : b2;
    const int j = i & 4095;
    if (*flagp) ((float*)dst)[i] = ((const float*)src)[j];
    else        ((bf16*)dst)[i]  = ((const bf16*)src)[j];
}

// ---------------------------------------------------------------------------
// 128^2-tile GEMM (verified rounds 0-1). Kept for the imf projection only.
__global__ __launch_bounds__(256, 3) void gemm_bt(
    const bf16* __restrict__ A, const bf16* __restrict__ Bt,
    void* __restrict__ Cv, const void* __restrict__ biasv,
    int K, int lda, int ldb, int ldc, float alpha,
    long long sAb, long long sAh, long long sBb, long long sBh,
    long long sCb, long long sCh,
    const int* __restrict__ flagp, int ebits)
{
    __shared__ bf16 sA[128 * 64];
    __shared__ bf16 sB[128 * 64];

    const int fl = ebits ? *flagp : 0;
    const bool bias32 = fl && (ebits & 1);
    const bool c32    = fl && (ebits & 2);

    const int z = blockIdx.z;
    const int bz = z >> 3, hz = z & 7;
    const bf16* Ab = A  + (size_t)bz * sAb + (size_t)hz * sAh;
    const bf16* Bb = Bt + (size_t)bz * sBb + (size_t)hz * sBh;
    const size_t offC = (size_t)bz * sCb + (size_t)hz * sCh;

    const int n0 = blockIdx.x * 128;
    const int m0 = blockIdx.y * 128;

    const int t = threadIdx.x;
    const int w = t >> 6, l = t & 63;
    const int lrow = l >> 3, lcol = l & 7;
    const int wm = (w >> 1) * 64, wn = (w & 1) * 64;
    const int ml = l & 15, quad = l >> 4;

    const bf16* pa[4];
    const bf16* pb[4];
    #pragma unroll
    for (int i = 0; i < 4; ++i) {
        const int c = w * 4 + i;
        const int r = c * 8 + lrow;
        const int jj = lcol ^ (r & 7);
        pa[i] = Ab + (size_t)(m0 + r) * lda + jj * 8;
        pb[i] = Bb + (size_t)(n0 + r) * ldb + jj * 8;
    }

    fx4 acc[4][4];
    const fx4 zero = {0.f, 0.f, 0.f, 0.f};
    #pragma unroll
    for (int i = 0; i < 4; ++i)
        #pragma unroll
        for (int j = 0; j < 4; ++j) acc[i][j] = zero;

    for (int kt = 0; kt < K; kt += 64) {
        #pragma unroll
        for (int i = 0; i < 4; ++i) {
            const int c = w * 4 + i;
            __builtin_amdgcn_global_load_lds((gv_t*)(pa[i] + kt), (lv_t*)(sA + c * 512), 16, 0, 0);
            __builtin_amdgcn_global_load_lds((gv_t*)(pb[i] + kt), (lv_t*)(sB + c * 512), 16, 0, 0);
        }
        __syncthreads();

        #pragma unroll
        for (int kk = 0; kk < 64; kk += 32) {
            bf16x8 af[4], bfr[4];
            const int jbase = (kk >> 3) + quad;
            #pragma unroll
            for (int mi = 0; mi < 4; ++mi) {
                const int r = wm + mi * 16 + ml;
                af[mi] = *(const bf16x8*)&sA[r * 64 + ((jbase ^ (r & 7)) << 3)];
            }
            #pragma unroll
            for (int ni = 0; ni < 4; ++ni) {
                const int r = wn + ni * 16 + ml;
                bfr[ni] = *(const bf16x8*)&sB[r * 64 + ((jbase ^ (r & 7)) << 3)];
            }
            #pragma unroll
            for (int mi = 0; mi < 4; ++mi)
                #pragma unroll
                for (int ni = 0; ni < 4; ++ni)
                    acc[mi][ni] = __builtin_amdgcn_mfma_f32_16x16x32_bf16(
                        af[mi], bfr[ni], acc[mi][ni], 0, 0, 0);
        }
        __syncthreads();
    }

    #pragma unroll
    for (int ni = 0; ni < 4; ++ni) {
        const int cg = n0 + wn + ni * 16 + ml;
        const float bv = biasv ? (bias32 ? ((const float*)biasv)[cg] : (float)((const bf16*)biasv)[cg]) : 0.f;
        #pragma unroll
        for (int mi = 0; mi < 4; ++mi) {
            const int rg = m0 + wm + mi * 16 + quad * 4;
            #pragma unroll
            for (int r = 0; r < 4; ++r) {
                const float val = acc[mi][ni][r] * alpha + bv;
                const size_t idx = offC + (size_t)(rg + r) * ldc + cg;
                if (c32) ((float*)Cv)[idx] = val;
                else     ((bf16*)Cv)[idx] = (bf16)val;
            }
        }
    }
}

// ---------------------------------------------------------------------------
// 256^2 per-phase-interleave GEMM (round-9 verified: 47% MfmaUtil). Structure
// UNCHANGED; only addition: `bstride` (bias z-stride in elems, 0 = shared) so
// the z=2 batched K/V projection can apply per-z biases. bstride=0 call sites
// are behavior-identical to round 9.
#define BARRIER   asm volatile("s_barrier" ::: "memory")
#define LGKM0     asm volatile("s_waitcnt lgkmcnt(0)" ::: "memory")
#define VM0       asm volatile("s_waitcnt vmcnt(0)" ::: "memory")
#define SCHED0    __builtin_amdgcn_sched_barrier(0)

// fragment load: row fr, k-group j=kI*4+quad, XOR slot swizzle (verified 0-conflict)
#define LDS_FRAG(dst, base, fr, kI)                                               \
    dst = *(const bf16x8*)&base[(fr) * 64 + ((((kI) * 4 + quad) ^ ((fr) & 7)) << 3)]

#define READ_A(dst, sX, roff)                                                     \
    _Pragma("unroll")                                                             \
    for (int im_ = 0; im_ < 4; ++im_)                                             \
        _Pragma("unroll")                                                         \
        for (int kI_ = 0; kI_ < 2; ++kI_)                                         \
            LDS_FRAG(dst[im_][kI_], sX, R0 + (roff) + im_ * 16 + ml, kI_);

#define READ_B(dst, sX, coff)                                                     \
    _Pragma("unroll")                                                             \
    for (int in_ = 0; in_ < 2; ++in_)                                             \
        _Pragma("unroll")                                                         \
        for (int kI_ = 0; kI_ < 2; ++kI_)                                         \
            LDS_FRAG(dst[in_][kI_], sX, C0 + (coff) + in_ * 16 + ml, kI_);

#define MFMA_Q(mo, no, afr_, bfr_)                                                \
    __builtin_amdgcn_s_setprio(1);                                                \
    _Pragma("unroll")                                                             \
    for (int kI_ = 0; kI_ < 2; ++kI_)                                             \
        _Pragma("unroll")                                                         \
        for (int im_ = 0; im_ < 4; ++im_)                                         \
            _Pragma("unroll")                                                     \
            for (int in_ = 0; in_ < 2; ++in_)                                     \
                acc[(mo) + im_][(no) + in_] =                                     \
                    __builtin_amdgcn_mfma_f32_16x16x32_bf16(                      \
                        afr_[im_][kI_], bfr_[in_][kI_],                           \
                        acc[(mo) + im_][(no) + in_], 0, 0, 0);                    \
    __builtin_amdgcn_s_setprio(0);

// stage both A-halves of tile ts into buffer sb (4 x 16B loads/thread)
#define STAGE_A(ts, sb)                                                           \
    do {                                                                          \
        _Pragma("unroll")                                                         \
        for (int h_ = 0; h_ < 2; ++h_)                                            \
            _Pragma("unroll")                                                     \
            for (int j_ = 0; j_ < 2; ++j_)                                        \
                __builtin_amdgcn_global_load_lds(                                 \
                    (gv_t*)(pA[h_][j_] + (size_t)(ts) * 64),                      \
                    (lv_t*)(&sm[sb][0][h_ * 8192 + (2 * w + j_) * 512]),          \
                    16, 0, 0);                                                    \
    } while (0)

// stage one B-half h of tile ts into buffer sb (2 x 16B loads/thread)
#define STAGE_B(ts, sb, h)                                                        \
    do {                                                                          \
        _Pragma("unroll")                                                         \
        for (int j_ = 0; j_ < 2; ++j_)                                            \
            __builtin_amdgcn_global_load_lds(                                     \
                (gv_t*)(pB[h][j_] + (size_t)(ts) * 64),                           \
                (lv_t*)(&sm[sb][1][(h) * 8192 + (2 * w + j_) * 512]),             \
                16, 0, 0);                                                        \
    } while (0)

#define HALF_ITER(cb, ts, sb, dostage)                                            \
    do {                                                                          \
        const bf16* sA_ = &sm[cb][0][0];                                          \
        const bf16* sB_ = &sm[cb][1][0];                                          \
        /* P1 */                                                                  \
        READ_A(afr, sA_, 0);                                                      \
        READ_B(b0r, sB_, 0);                                                      \
        if (dostage) { STAGE_A(ts, sb); }                                         \
        BARRIER; LGKM0; SCHED0;                                                   \
        MFMA_Q(0, 0, afr, b0r);                                                   \
        BARRIER;                                                                  \
        /* P2 */                                                                  \
        READ_B(b1r, sB_, 32);                                                     \
        if (dostage) { STAGE_B(ts, sb, 0); }                                      \
        BARRIER; LGKM0; SCHED0;                                                   \
        MFMA_Q(0, 2, afr, b1r);                                                   \
        BARRIER;                                                                  \
        /* P3 */                                                                  \
        READ_A(afr, sA_, 64);                                                     \
        if (dostage) { STAGE_B(ts, sb, 1); }                                      \
        BARRIER; LGKM0; SCHED0;                                                   \
        MFMA_Q(4, 2, afr, b1r);                                                   \
        BARRIER;                                                                  \
        /* P4: pure MFMA; drain staged DMA; buffer handoff */                     \
        MFMA_Q(4, 0, afr, b0r);                                                   \
        VM0;                                                                      \
        BARRIER;                                                                  \
    } while (0)

__global__ __launch_bounds__(512, 2) void gemm256(
    const bf16* __restrict__ A, const bf16* __restrict__ Bt,
    void* __restrict__ Cv, const void* __restrict__ biasv,
    int K, int lda, int ldb, int ldc, float alpha,
    long long sAb, long long sAh, long long sBb, long long sBh,
    long long sCb, long long sCh,
    const int* __restrict__ flagp, int ebits, int bstride)
{
    __shared__ bf16 sm[2][2][256 * 64];   // [buf][A/B][tile] = 128 KiB

    const int fl = ebits ? *flagp : 0;
    const bool bias32 = fl && (ebits & 1);
    const bool c32    = fl && (ebits & 2);

    // ---- XCD-bijective block swizzle (all grids here are %8==0) ----
    const int gX = gridDim.x, gY = gridDim.y;
    int idx = (blockIdx.z * gY + blockIdx.y) * gX + blockIdx.x;
    const int nwg = gX * gY * gridDim.z;
    if ((nwg & 7) == 0) idx = (idx & 7) * (nwg >> 3) + (idx >> 3);
    const int bx = idx % gX;
    const int tmpi = idx / gX;
    const int by = tmpi % gY;
    const int z  = tmpi / gY;

    const int bz = z >> 3, hz = z & 7;
    const bf16* Ab = A  + (size_t)bz * sAb + (size_t)hz * sAh;
    const bf16* Bb = Bt + (size_t)bz * sBb + (size_t)hz * sBh;
    const size_t offC = (size_t)bz * sCb + (size_t)hz * sCh;

    const int n0 = bx * 256;
    const int m0 = by * 256;

    const int t  = threadIdx.x;
    const int w  = t >> 6, l = t & 63;
    const int lrow = l >> 3, lcol = l & 7;          // staging decomposition
    const int wr = w >> 2, wc = w & 3;              // wave grid 2x4
    const int R0 = wr * 128, C0 = wc * 64;          // per-wave C sub-tile
    const int ml = l & 15, quad = l >> 4;           // MFMA fragment lanes

    // staging pointers: half h (128 rows), load j -> chunk 2w+j of that half
    const bf16* pA[2][2];
    const bf16* pB[2][2];
    #pragma unroll
    for (int h = 0; h < 2; ++h)
        #pragma unroll
        for (int j = 0; j < 2; ++j) {
            const int r = h * 128 + (2 * w + j) * 8 + lrow;
            const int jj = lcol ^ (r & 7);
            pA[h][j] = Ab + (size_t)(m0 + r) * lda + jj * 8;
            pB[h][j] = Bb + (size_t)(n0 + r) * ldb + jj * 8;
        }

    fx4 acc[8][4];
    const fx4 zero = {0.f, 0.f, 0.f, 0.f};
    #pragma unroll
    for (int i = 0; i < 8; ++i)
        #pragma unroll
        for (int j = 0; j < 4; ++j) acc[i][j] = zero;

    bf16x8 afr[4][2], b0r[2][2], b1r[2][2];

    const int nt  = K >> 6;    // K-tiles of 64 (8 or 64 here -> always even)
    const int nit = nt >> 1;   // iterations of 2 K-tiles

    // ---- prologue: stage tile 0 -> buf0 fully; drain; sync ----
    STAGE_A(0, 0);
    STAGE_B(0, 0, 0);
    STAGE_B(0, 0, 1);
    VM0;
    BARRIER;

    for (int it = 0; it < nit; ++it) {
        // consume tile 2it (buf0); stage tile 2it+1 -> buf1 (consumed next half)
        HALF_ITER(0, 2 * it + 1, 1, true);
        // consume tile 2it+1 (buf1); stage tile 2it+2 -> buf0 (next iteration)
        HALF_ITER(1, 2 * it + 2, 0, (it + 1 < nit));
    }

    // ---- epilogue: C/D layout col=lane&15, row=(lane>>4)*4+reg ----
    #pragma unroll
    for (int ni = 0; ni < 4; ++ni) {
        const int cg = n0 + C0 + ni * 16 + ml;
        const int bix = hz * bstride + cg;
        const float bv = biasv ? (bias32 ? ((const float*)biasv)[bix] : (float)((const bf16*)biasv)[bix]) : 0.f;
        #pragma unroll
        for (int mi = 0; mi < 8; ++mi) {
            const int rg = m0 + R0 + mi * 16 + quad * 4;
            #pragma unroll
            for (int r = 0; r < 4; ++r) {
                const float val = acc[mi][ni][r] * alpha + bv;
                const size_t idx = offC + (size_t)(rg + r) * ldc + cg;
                if (c32) ((float*)Cv)[idx] = val;
                else     ((bf16*)Cv)[idx] = (bf16)val;
            }
        }
    }
}

// In-place row softmax, rows of exactly 512 bf16. One wave per row (8 elems/lane).
__global__ __launch_bounds__(256) void softmax512(bf16* __restrict__ buf)
{
    const int row = blockIdx.x * 4 + (threadIdx.x >> 6);
    const int l = threadIdx.x & 63;
    bf16* p = buf + (size_t)row * 512 + l * 8;
    bf16x8 v = *(const bf16x8*)p;
    float f[8];
    float mx = -1e30f;
    #pragma unroll
    for (int j = 0; j < 8; ++j) {
        f[j] = (float)v[j];
        if (!(fabsf(f[j]) < 1e30f)) f[j] = -1e9f;   // NaN/Inf guard
        mx = fmaxf(mx, f[j]);
    }
    #pragma unroll
    for (int s = 1; s < 64; s <<= 1) mx = fmaxf(mx, __shfl_xor(mx, s));
    float sum = 0.f;
    #pragma unroll
    for (int j = 0; j < 8; ++j) { f[j] = __expf(f[j] - mx); sum += f[j]; }
    #pragma unroll
    for (int s = 1; s < 64; s <<= 1) sum += __shfl_xor(sum, s);
    const float inv = 1.f / sum;
    #pragma unroll
    for (int j = 0; j < 8; ++j) v[j] = (bf16)(f[j] * inv);
    *(bf16x8*)p = v;
}

// out[z][d][s] = in[b][s][h*512+d], z = b*8+h. 32x32 tiles via LDS. (internal bf16)
__global__ __launch_bounds__(256) void transpose_heads(
    const bf16* __restrict__ in, bf16* __restrict__ out)
{
    __shared__ bf16 tile[32][33];
    const int z = blockIdx.z, b = z >> 3, h = z & 7;
    const int s0 = blockIdx.x * 32, d0 = blockIdx.y * 32;
    const int tx = threadIdx.x, ty = threadIdx.y;   // 32 x 8
    #pragma unroll
    for (int j = 0; j < 4; ++j) {
        const int s = s0 + ty + j * 8;
        tile[ty + j * 8][tx] = in[(size_t)b * SK_ * DM_ + (size_t)s * DM_ + h * DK_ + d0 + tx];
    }
    __syncthreads();
    #pragma unroll
    for (int j = 0; j < 4; ++j) {
        const int d = d0 + ty + j * 8;
        out[(size_t)z * DK_ * SK_ + (size_t)d * SK_ + s0 + tx] = tile[tx][ty + j * 8];
    }
}

extern "C" void kernel_launch(void* const* d_in, const int* in_sizes, int n_in,
                              void* d_out, int out_size, void* d_ws, size_t ws_size,
                              hipStream_t stream)
{
    const void* query = d_in[0];
    const void* key   = d_in[1];
    const void* value = d_in[2];
    const void* imf   = d_in[3];
    const void* W0 = d_in[4];  const void* b0 = d_in[5];
    const void* W1 = d_in[6];  const void* b1 = d_in[7];
    const void* W2 = d_in[8];  const void* b2 = d_in[9];
    const void* W3 = d_in[10]; const void* b3 = d_in[11];

    // ---- workspace (bf16 elems; >=58.7M proven). Liveness-audited offsets:
    bf16* ws    = (bf16*)d_ws;
    int*  flagp = (int*)d_ws;
    bf16* wS1   = ws + 8;                    // 16.8M: W0 -> W1 -> (vT,imfT) -> W3final
    bf16* wS2   = ws + 16777224;             // 16.8M: W2 -> W3 -> s1/xcat start
    bf16* vT    = ws + 8;                    //  8.4M (W slots dead after KV GEMM)
    bf16* imfT  = ws + 8388616;              //  8.4M
    bf16* w3s   = ws + 16777224;             // 16.8M (dead after imf GEMM)
    bf16* imfp  = ws + 33554440;             //  8.4M (dead after transpose)
    bf16* s1    = ws + 16777224;             // 33.5M (overlays dead w3s+imfp; ends 50.3M)
    bf16* xcat  = ws + 16777224;             // 33.5M (overlays dead s1)
    bf16* w3f   = ws + 8;                    // 16.8M (after vT/imfT die)
    bf16* wbias = ws + 50331656;             // 16K: staged b1|b2 (dtype follows flag)

    // ---- d_out (67.1M bf16 elems), multi-duty until final GEMM fills it ----
    bf16* obase = (bf16*)d_out;
    bf16* qproj = obase;                     // 33.5M (dead after scores GEMM)
    bf16* qbf   = obase + 33554432;          // 33.5M (dead after Q proj)
    bf16* kin   = obase + 33554432;          //  8.4M (k/v contiguous inputs)
    bf16* vin   = obase + 41943040;          //  8.4M
    bf16* iin   = obase + 33554432;          //  8.4M (reuses dead kin)
    bf16* kproj = obase + 50331648;          //  8.4M (kproj/vproj contiguous, sCh=8.4M)
    bf16* vproj = obase + 58720256;          //  8.4M (dead after transpose)
    bf16* s2    = obase + 33554432;          // 33.5M (after iin/vin/kproj/vproj die)

    const float inv_sqrt_dk = 0.04419417382415922f;  // 1/sqrt(512)

    // 0: decide external dtype (fp32 vs bf16) from query's bit patterns
    sniff_dtype<<<1, 64, 0, stream>>>((const uint32_t*)query, flagp);

    // ---- Q path: convert, project (16x32 = 512 WGs = 2 full rounds) ----
    cvt_to_bf16<<<16384, 256, 0, stream>>>(query, qbf, flagp);
    cvt_to_bf16<<<8192, 256, 0, stream>>>(W0, wS1, flagp);
    gemm256<<<dim3(16, 32, 1), 512, 0, stream>>>(qbf, wS1, qproj, b0,
        4096, 4096, 4096, 4096, 1.f, 0,0,0,0,0,0, flagp, 1, 0);

    // ---- K+V batched projection: z=2, grid (16,8,2) = 256 WGs = 1 WG/CU
    //      (perfect fill on the 47% kernel; replaces 2x gemm_bt @ ~35%).
    //      Weights contiguous (sBh=16.8M), inputs contiguous (sAh=8.4M),
    //      outputs contiguous (sCh=8.4M), per-z bias via bstride=4096. ----
    cvt_to_bf16<<<4096, 256, 0, stream>>>(key, kin, flagp);
    cvt_to_bf16<<<4096, 256, 0, stream>>>(value, vin, flagp);
    cvt_to_bf16<<<8192, 256, 0, stream>>>(W1, wS1, flagp);
    cvt_to_bf16<<<8192, 256, 0, stream>>>(W2, wS2, flagp);
    copy_bias2<<<32, 256, 0, stream>>>(b1, b2, wbias, flagp);
    gemm256<<<dim3(16, 8, 2), 512, 0, stream>>>(kin, wS1, kproj, wbias,
        4096, 4096, 4096, 4096, 1.f,
        0LL, 8388608LL, 0LL, 16777216LL, 0LL, 8388608LL,
        flagp, 1, 4096);

    // ---- imf projection (gemm_bt: 512 WGs fills better than 128-WG 256^2) ----
    cvt_to_bf16<<<4096, 256, 0, stream>>>(imf, iin, flagp);
    cvt_to_bf16<<<8192, 256, 0, stream>>>(W3, w3s, flagp);
    gemm_bt<<<dim3(32, 16, 1), 256, 0, stream>>>(iin, w3s, imfp, b3,
        4096, 4096, 4096, 4096, 1.f, 0,0,0,0,0,0, flagp, 1);

    // ---- per-head transposes so the @imf and @v einsums become A·B^T ----
    transpose_heads<<<dim3(16, 16, 32), dim3(32, 8), 0, stream>>>(vproj, vT);
    transpose_heads<<<dim3(16, 16, 32), dim3(32, 8), 0, stream>>>(imfp, imfT);

    // ---- scores = q·k^T / sqrt(dk)  (2x8x32 = 512 WGs) ----
    gemm256<<<dim3(2, 8, 32), 512, 0, stream>>>(qproj, kproj, s1, nullptr,
        512, 4096, 4096, 512, inv_sqrt_dk,
        (long long)SQ_*DM_, (long long)DK_, (long long)SK_*DM_, (long long)DK_,
        (long long)H_*SQ_*SK_, (long long)SQ_*SK_, flagp, 0, 0);
    softmax512<<<dim3(16384), 256, 0, stream>>>(s1);
    // ---- s2 = p @ imf_h ----
    gemm256<<<dim3(2, 8, 32), 512, 0, stream>>>(s1, imfT, s2, nullptr,
        512, 512, 512, 512, 1.f,
        (long long)H_*SQ_*SK_, (long long)SQ_*SK_, (long long)H_*DK_*SK_, (long long)DK_*SK_,
        (long long)H_*SQ_*SK_, (long long)SQ_*SK_, flagp, 0, 0);
    softmax512<<<dim3(16384), 256, 0, stream>>>(s2);
    // ---- x = im_attn @ v_h -> concat-head layout (xcat overlays dead s1) ----
    gemm256<<<dim3(2, 8, 32), 512, 0, stream>>>(s2, vT, xcat, nullptr,
        512, 512, 512, 4096, 1.f,
        (long long)H_*SQ_*SK_, (long long)SQ_*SK_, (long long)H_*DK_*SK_, (long long)DK_*SK_,
        (long long)SQ_*DM_, (long long)DK_, flagp, 0, 0);
    // ---- out = xcat @ W3^T + b3 (re-convert W3 into dead vT/imfT region) ----
    cvt_to_bf16<<<8192, 256, 0, stream>>>(W3, w3f, flagp);
    gemm256<<<dim3(16, 32, 1), 512, 0, stream>>>(xcat, w3f, d_out, b3,
        4096, 4096, 4096, 4096, 1.f, 0,0,0,0,0,0, flagp, 3, 0);
}